// Round 3
// baseline (284.434 us; speedup 1.0000x reference)
//
#include <hip/hip_runtime.h>
#include <hip/hip_bf16.h>

// Problem constants
#define B_      64
#define C_      3
#define H_      224
#define W_      224
#define P_      (H_*W_)      // 50176 pixels per image
#define S_      196          // MAX_SEGMENTS
#define MAXPIX  400
#define E_      768          // EMBED
#define K_      1200         // C*MAXPIX
#define KP_     1216         // K padded to multiple of 32
#define CHUNK_  512
#define NCH_    (P_/CHUNK_)  // 98 chunks per image
#define M_      (B_*S_)      // 12544 GEMM rows

typedef __attribute__((ext_vector_type(8))) short short8;
typedef __attribute__((ext_vector_type(4))) float f32x4;

__device__ inline unsigned short f2bf(float f) {
  union { float f; unsigned int u; } x; x.f = f;
  return (unsigned short)((x.u + 0x7fffu + ((x.u >> 16) & 1u)) >> 16);
}

// ---------------- zero scratch (feats buffer) ----------------
__global__ void zero_k(int4* __restrict__ p, int n4) {
  int i = blockIdx.x * blockDim.x + threadIdx.x;
  int stride = gridDim.x * blockDim.x;
  int4 z = make_int4(0, 0, 0, 0);
  for (; i < n4; i += stride) p[i] = z;
}

// ---------------- W fp32 -> bf16 with K-padding ----------------
__global__ void wconv_k(const float* __restrict__ Wf, unsigned short* __restrict__ Wb) {
  int idx = blockIdx.x * 256 + threadIdx.x;     // 0 .. E_*KP_ (exact grid)
  int e = idx / KP_, k = idx - e * KP_;
  float v = (k < K_) ? Wf[e * K_ + k] : 0.f;
  Wb[idx] = f2bf(v);
}

// ---------------- per-chunk rank + histogram ----------------
// grid: B_*NCH_ blocks, 512 threads. Within-wave rank via shfl match-count,
// cross-wave offset via per-wave LDS histograms.
__global__ __launch_bounds__(512) void rank_k(const int* __restrict__ seg,
                                              int* __restrict__ hist,
                                              unsigned short* __restrict__ rloc) {
  int b = blockIdx.x / NCH_, ch = blockIdx.x % NCH_;
  int tid = threadIdx.x, wave = tid >> 6, lane = tid & 63;
  int p = ch * CHUNK_ + tid;
  int s = seg[b * P_ + p];

  __shared__ int lhist[8][S_];
  for (int i = tid; i < 8 * S_; i += 512) ((int*)lhist)[i] = 0;
  __syncthreads();

  // count earlier lanes in this wave with the same segment id
  int r = 0;
  #pragma unroll 1
  for (int j = 0; j < 64; ++j) {
    int sj = __shfl(s, j);
    r += (j < lane && sj == s) ? 1 : 0;
  }
  atomicAdd(&lhist[wave][s], 1);
  __syncthreads();

  int off = 0;
  for (int w2 = 0; w2 < wave; ++w2) off += lhist[w2][s];
  rloc[b * P_ + p] = (unsigned short)(off + r);

  if (tid < S_) {
    int t = 0;
    #pragma unroll
    for (int w2 = 0; w2 < 8; ++w2) t += lhist[w2][tid];
    hist[(b * NCH_ + ch) * S_ + tid] = t;
  }
}

// ---------------- exclusive prefix over chunks per (b, s) ----------------
__global__ void prefix_k(int* __restrict__ hist) {
  int b = blockIdx.x;
  int s = threadIdx.x;
  if (s >= S_) return;
  int acc = 0;
  for (int c = 0; c < NCH_; ++c) {
    int* ptr = &hist[(b * NCH_ + c) * S_ + s];
    int v = *ptr;
    *ptr = acc;
    acc += v;
  }
}

// ---------------- scatter img -> padded bf16 feats ----------------
__global__ void scatter_k(const float* __restrict__ img, const int* __restrict__ seg,
                          const int* __restrict__ starts, const unsigned short* __restrict__ rloc,
                          unsigned short* __restrict__ feats) {
  int b = blockIdx.x / (P_ / 256);
  int p = (blockIdx.x % (P_ / 256)) * 256 + threadIdx.x;
  int s = seg[b * P_ + p];
  int rank = starts[(b * NCH_ + (p >> 9)) * S_ + s] + rloc[b * P_ + p];
  if (rank < MAXPIX) {
    size_t row = (size_t)(b * S_ + s) * KP_;
    const float* ip = img + (size_t)b * C_ * P_ + p;
    feats[row + rank]              = f2bf(ip[0]);
    feats[row + MAXPIX + rank]     = f2bf(ip[P_]);
    feats[row + 2 * MAXPIX + rank] = f2bf(ip[2 * P_]);
  }
}

// ---------------- bf16 MFMA GEMM: out[M][E] = feats[M][KP] * Wb[E][KP]^T + bias ----------------
// 128x128 tile, 4 waves (2x2), each wave 64x64 = 4x4 of 16x16x32 MFMA.
__global__ __launch_bounds__(256) void gemm_k(const unsigned short* __restrict__ A,
                                              const unsigned short* __restrict__ Bw,
                                              const float* __restrict__ bias,
                                              float* __restrict__ out) {
  const int nb = blockIdx.x % (E_ / 128);   // 0..5
  const int mb = blockIdx.x / (E_ / 128);   // 0..97
  const int tid = threadIdx.x;
  const int w = tid >> 6, l = tid & 63;
  const int wr = w >> 1, wc = w & 1;

  __shared__ __align__(16) unsigned short As[128 * 32];
  __shared__ __align__(16) unsigned short Bs[128 * 32];

  f32x4 acc[4][4] = {};

  const int lrow = l >> 2;        // 0..15
  const int lcol = (l & 3) * 8;   // element offset within 32-wide K slice
  const int kk = (l >> 4) * 8;    // fragment K offset

  for (int k0 = 0; k0 < KP_; k0 += 32) {
    #pragma unroll
    for (int q = 0; q < 2; ++q) {
      int r = (w * 2 + q) * 16 + lrow;
      const unsigned short* ga = A + (size_t)(mb * 128 + r) * KP_ + k0 + lcol;
      __builtin_amdgcn_global_load_lds((const __attribute__((address_space(1))) unsigned int*)ga,
                                       (__attribute__((address_space(3))) unsigned int*)&As[(w * 2 + q) * 512],
                                       16, 0, 0);
      const unsigned short* gb = Bw + (size_t)(nb * 128 + r) * KP_ + k0 + lcol;
      __builtin_amdgcn_global_load_lds((const __attribute__((address_space(1))) unsigned int*)gb,
                                       (__attribute__((address_space(3))) unsigned int*)&Bs[(w * 2 + q) * 512],
                                       16, 0, 0);
    }
    __syncthreads();

    short8 af[4], bf[4];
    #pragma unroll
    for (int mi = 0; mi < 4; ++mi)
      af[mi] = *(const short8*)&As[(wr * 64 + mi * 16 + (l & 15)) * 32 + kk];
    #pragma unroll
    for (int ni = 0; ni < 4; ++ni)
      bf[ni] = *(const short8*)&Bs[(wc * 64 + ni * 16 + (l & 15)) * 32 + kk];
    #pragma unroll
    for (int mi = 0; mi < 4; ++mi)
      #pragma unroll
      for (int ni = 0; ni < 4; ++ni)
        acc[mi][ni] = __builtin_amdgcn_mfma_f32_16x16x32_bf16(af[mi], bf[ni], acc[mi][ni], 0, 0, 0);
    __syncthreads();
  }

  // epilogue: C/D layout col = lane&15, row = (lane>>4)*4 + reg  [verified m89/m91]
  const int r0 = (l >> 4) * 4;
  const int c0 = l & 15;
  #pragma unroll
  for (int mi = 0; mi < 4; ++mi) {
    #pragma unroll
    for (int ni = 0; ni < 4; ++ni) {
      int col = nb * 128 + wc * 64 + ni * 16 + c0;
      float bv = bias[col];
      int row = mb * 128 + wr * 64 + mi * 16 + r0;
      #pragma unroll
      for (int r = 0; r < 4; ++r)
        out[(size_t)(row + r) * E_ + col] = acc[mi][ni][r] + bv;
    }
  }
}

extern "C" void kernel_launch(void* const* d_in, const int* in_sizes, int n_in,
                              void* d_out, int out_size, void* d_ws, size_t ws_size,
                              hipStream_t stream) {
  const float* img  = (const float*)d_in[0];   // [64,3,224,224]
  const int*   seg  = (const int*)d_in[1];     // [64,224,224]
  const float* Wf   = (const float*)d_in[2];   // [768,1200]
  const float* bias = (const float*)d_in[3];   // [768]
  float* out = (float*)d_out;                  // [64,196,768]

  // workspace layout (total ~43.7 MB)
  constexpr size_t FEATS_BYTES = (size_t)M_ * KP_ * 2;      // 30,507,008
  constexpr size_t WB_BYTES    = (size_t)E_ * KP_ * 2;      //  1,867,776
  constexpr size_t HIST_BYTES  = (size_t)B_ * NCH_ * S_ * 4;//  4,917,248
  char* ws = (char*)d_ws;
  unsigned short* feats = (unsigned short*)ws;
  unsigned short* Wb    = (unsigned short*)(ws + FEATS_BYTES);
  int*            hist  = (int*)(ws + FEATS_BYTES + WB_BYTES);
  unsigned short* rloc  = (unsigned short*)(ws + FEATS_BYTES + WB_BYTES + HIST_BYTES);

  zero_k<<<2048, 256, 0, stream>>>((int4*)feats, (int)(FEATS_BYTES / 16));
  wconv_k<<<(E_ * KP_) / 256, 256, 0, stream>>>(Wf, Wb);
  rank_k<<<B_ * NCH_, 512, 0, stream>>>(seg, hist, rloc);
  prefix_k<<<B_, 256, 0, stream>>>(hist);
  scatter_k<<<B_ * (P_ / 256), 256, 0, stream>>>(img, seg, hist, rloc, feats);
  gemm_k<<<(M_ / 128) * (E_ / 128), 256, 0, stream>>>(feats, Wb, bias, out);
}

// Round 4
// 253.937 us; speedup vs baseline: 1.1201x; 1.1201x over previous
//
#include <hip/hip_runtime.h>
#include <hip/hip_bf16.h>

// Problem constants
#define B_      64
#define C_      3
#define H_      224
#define W_      224
#define P_      (H_*W_)      // 50176 pixels per image
#define S_      196          // MAX_SEGMENTS
#define MAXPIX  400
#define E_      768          // EMBED
#define K_      1200         // C*MAXPIX
#define KP_     1216         // K padded to multiple of 32
#define CHUNK_  512
#define NCH_    (P_/CHUNK_)  // 98 chunks per image
#define M_      (B_*S_)      // 12544 GEMM rows

typedef __attribute__((ext_vector_type(8))) short short8;
typedef __attribute__((ext_vector_type(4))) float f32x4;

__device__ inline unsigned short f2bf(float f) {
  union { float f; unsigned int u; } x; x.f = f;
  return (unsigned short)((x.u + 0x7fffu + ((x.u >> 16) & 1u)) >> 16);
}

// chunked XCD swizzle, nwg % 8 == 0: XCD k owns a contiguous span of nwg/8 blocks
__device__ inline int xcd_chunk(int wg, int nwg) {
  int q = nwg >> 3;
  return (wg & 7) * q + (wg >> 3);
}

// ---------------- W fp32 -> bf16 with K-padding ----------------
__global__ void wconv_k(const float* __restrict__ Wf, unsigned short* __restrict__ Wb) {
  int idx = blockIdx.x * 256 + threadIdx.x;     // 0 .. E_*KP_ (exact grid)
  int e = idx / KP_, k = idx - e * KP_;
  float v = (k < K_) ? Wf[e * K_ + k] : 0.f;
  Wb[idx] = f2bf(v);
}

// ---------------- per-chunk rank + histogram ----------------
__global__ __launch_bounds__(512) void rank_k(const int* __restrict__ seg,
                                              int* __restrict__ hist,
                                              unsigned short* __restrict__ rloc) {
  int b = blockIdx.x / NCH_, ch = blockIdx.x % NCH_;
  int tid = threadIdx.x, wave = tid >> 6, lane = tid & 63;
  int p = ch * CHUNK_ + tid;
  int s = seg[b * P_ + p];

  __shared__ int lhist[8][S_];
  for (int i = tid; i < 8 * S_; i += 512) ((int*)lhist)[i] = 0;
  __syncthreads();

  // count earlier lanes in this wave with the same segment id (stable raster rank)
  int r = 0;
  #pragma unroll 1
  for (int j = 0; j < 64; ++j) {
    int sj = __shfl(s, j);
    r += (j < lane && sj == s) ? 1 : 0;
  }
  atomicAdd(&lhist[wave][s], 1);
  __syncthreads();

  int off = 0;
  for (int w2 = 0; w2 < wave; ++w2) off += lhist[w2][s];
  rloc[b * P_ + p] = (unsigned short)(off + r);

  if (tid < S_) {
    int t = 0;
    #pragma unroll
    for (int w2 = 0; w2 < 8; ++w2) t += lhist[w2][tid];
    hist[(b * NCH_ + ch) * S_ + tid] = t;
  }
}

// ---------------- parallel exclusive prefix over chunks per (b, s) ----------------
// grid: B_*S_ blocks, 128 threads: Hillis-Steele scan over the 98 chunk counts.
__global__ __launch_bounds__(128) void prefix_k(int* __restrict__ hist, int* __restrict__ cnts) {
  int b = blockIdx.x / S_, s = blockIdx.x % S_;
  int t = threadIdx.x;
  __shared__ int sc[128];
  int v = (t < NCH_) ? hist[(b * NCH_ + t) * S_ + s] : 0;
  sc[t] = v;
  __syncthreads();
  #pragma unroll
  for (int off = 1; off < 128; off <<= 1) {
    int x = (t >= off) ? sc[t - off] : 0;
    __syncthreads();
    sc[t] += x;
    __syncthreads();
  }
  if (t < NCH_) hist[(b * NCH_ + t) * S_ + s] = sc[t] - v;   // exclusive
  if (t == NCH_ - 1) {
    int tot = sc[t];
    cnts[b * S_ + s] = tot < MAXPIX ? tot : MAXPIX;
  }
}

// ---------------- scatter pixel ids -> inv[b][s][rank] (uint16) ----------------
__global__ __launch_bounds__(256) void scatter_inv_k(const int* __restrict__ seg,
                                                     const int* __restrict__ starts,
                                                     const unsigned short* __restrict__ rloc,
                                                     unsigned short* __restrict__ inv) {
  int wg = xcd_chunk(blockIdx.x, B_ * (P_ / 256));   // contiguous pixel span per XCD
  int b = wg / (P_ / 256);
  int p = (wg % (P_ / 256)) * 256 + threadIdx.x;
  int s = seg[b * P_ + p];
  int rank = starts[(b * NCH_ + (p >> 9)) * S_ + s] + rloc[b * P_ + p];
  if (rank < MAXPIX)
    inv[(b * S_ + s) * MAXPIX + rank] = (unsigned short)p;
}

// ---------------- gather img -> feats rows (dense, coalesced writes) ----------------
// one block per (b,s) row; writes the ENTIRE KP_-wide row incl. padding zeros.
__global__ __launch_bounds__(256) void gather_k(const float* __restrict__ img,
                                                const unsigned short* __restrict__ inv,
                                                const int* __restrict__ cnts,
                                                unsigned short* __restrict__ feats) {
  int wg = xcd_chunk(blockIdx.x, M_);   // ~8 images per XCD -> img L2-resident
  int b = wg / S_, s = wg % S_;
  int t = threadIdx.x;
  int cnt = cnts[b * S_ + s];
  const unsigned short* invrow = inv + (size_t)(b * S_ + s) * MAXPIX;
  unsigned short* frow = feats + (size_t)(b * S_ + s) * KP_;
  #pragma unroll
  for (int c = 0; c < C_; ++c) {
    const float* ic = img + ((size_t)b * C_ + c) * P_;
    for (int r = t; r < MAXPIX; r += 256) {
      int p = invrow[r];                       // garbage beyond cnt -- gated below
      float v = (r < cnt) ? ic[p] : 0.f;
      frow[c * MAXPIX + r] = f2bf(v);
    }
  }
  if (t < KP_ - K_) frow[K_ + t] = 0;          // K padding
}

// ---------------- bf16 MFMA GEMM: out[M][E] = feats[M][KP] * Wb[E][KP]^T + bias ----------------
__global__ __launch_bounds__(256) void gemm_k(const unsigned short* __restrict__ A,
                                              const unsigned short* __restrict__ Bw,
                                              const float* __restrict__ bias,
                                              float* __restrict__ out) {
  // bijective chunked swizzle (m204): nwg=588, q=73, r=4 -> blocks sharing an
  // A-panel (6 consecutive) land on one XCD
  int bid;
  {
    int wg = blockIdx.x, q = 588 / 8, r = 588 % 8;
    int xcd = wg % 8, idx = wg / 8;
    bid = (xcd < r) ? xcd * (q + 1) + idx : r * (q + 1) + (xcd - r) * q + idx;
  }
  const int nb = bid % (E_ / 128);   // 0..5
  const int mb = bid / (E_ / 128);   // 0..97
  const int tid = threadIdx.x;
  const int w = tid >> 6, l = tid & 63;
  const int wr = w >> 1, wc = w & 1;

  __shared__ __align__(16) unsigned short As[128 * 32];
  __shared__ __align__(16) unsigned short Bs[128 * 32];

  f32x4 acc[4][4] = {};

  const int lrow = l >> 2;        // 0..15
  const int lcol = (l & 3) * 8;   // element offset within 32-wide K slice
  const int kk = (l >> 4) * 8;    // fragment K offset

  for (int k0 = 0; k0 < KP_; k0 += 32) {
    #pragma unroll
    for (int q = 0; q < 2; ++q) {
      int r = (w * 2 + q) * 16 + lrow;
      const unsigned short* ga = A + (size_t)(mb * 128 + r) * KP_ + k0 + lcol;
      __builtin_amdgcn_global_load_lds((const __attribute__((address_space(1))) unsigned int*)ga,
                                       (__attribute__((address_space(3))) unsigned int*)&As[(w * 2 + q) * 512],
                                       16, 0, 0);
      const unsigned short* gb = Bw + (size_t)(nb * 128 + r) * KP_ + k0 + lcol;
      __builtin_amdgcn_global_load_lds((const __attribute__((address_space(1))) unsigned int*)gb,
                                       (__attribute__((address_space(3))) unsigned int*)&Bs[(w * 2 + q) * 512],
                                       16, 0, 0);
    }
    __syncthreads();

    short8 af[4], bf[4];
    #pragma unroll
    for (int mi = 0; mi < 4; ++mi)
      af[mi] = *(const short8*)&As[(wr * 64 + mi * 16 + (l & 15)) * 32 + kk];
    #pragma unroll
    for (int ni = 0; ni < 4; ++ni)
      bf[ni] = *(const short8*)&Bs[(wc * 64 + ni * 16 + (l & 15)) * 32 + kk];
    #pragma unroll
    for (int mi = 0; mi < 4; ++mi)
      #pragma unroll
      for (int ni = 0; ni < 4; ++ni)
        acc[mi][ni] = __builtin_amdgcn_mfma_f32_16x16x32_bf16(af[mi], bf[ni], acc[mi][ni], 0, 0, 0);
    __syncthreads();
  }

  // epilogue: C/D layout col = lane&15, row = (lane>>4)*4 + reg  [verified m89/m91]
  const int r0 = (l >> 4) * 4;
  const int c0 = l & 15;
  #pragma unroll
  for (int mi = 0; mi < 4; ++mi) {
    #pragma unroll
    for (int ni = 0; ni < 4; ++ni) {
      int col = nb * 128 + wc * 64 + ni * 16 + c0;
      float bv = bias[col];
      int row = mb * 128 + wr * 64 + mi * 16 + r0;
      #pragma unroll
      for (int r = 0; r < 4; ++r)
        out[(size_t)(row + r) * E_ + col] = acc[mi][ni][r] + bv;
    }
  }
}

extern "C" void kernel_launch(void* const* d_in, const int* in_sizes, int n_in,
                              void* d_out, int out_size, void* d_ws, size_t ws_size,
                              hipStream_t stream) {
  const float* img  = (const float*)d_in[0];   // [64,3,224,224]
  const int*   seg  = (const int*)d_in[1];     // [64,224,224]
  const float* Wf   = (const float*)d_in[2];   // [768,1200]
  const float* bias = (const float*)d_in[3];   // [768]
  float* out = (float*)d_out;                  // [64,196,768]

  // workspace layout with lifetime overlap (total 42.5 MB):
  //   [Wb 1.87M][inv 10.04M][cnts 0.05M][feats 30.5M]
  //   rloc/hist live inside the feats region (dead before gather_k writes feats)
  constexpr size_t WB_BYTES    = (size_t)E_ * KP_ * 2;        //  1,867,776
  constexpr size_t INV_BYTES   = (size_t)M_ * MAXPIX * 2;     // 10,035,200
  constexpr size_t CNT_BYTES   = (size_t)M_ * 4;              //     50,176
  constexpr size_t RLOC_BYTES  = (size_t)B_ * P_ * 2;         //  6,422,528
  char* ws = (char*)d_ws;
  unsigned short* Wb    = (unsigned short*)ws;
  unsigned short* inv   = (unsigned short*)(ws + WB_BYTES);
  int*            cnts  = (int*)(ws + WB_BYTES + INV_BYTES);
  unsigned short* feats = (unsigned short*)(ws + WB_BYTES + INV_BYTES + CNT_BYTES);
  unsigned short* rloc  = feats;                                      // overlaid
  int*            hist  = (int*)((char*)feats + RLOC_BYTES);          // overlaid

  wconv_k<<<(E_ * KP_) / 256, 256, 0, stream>>>(Wf, Wb);
  rank_k<<<B_ * NCH_, 512, 0, stream>>>(seg, hist, rloc);
  prefix_k<<<B_ * S_, 128, 0, stream>>>(hist, cnts);
  scatter_inv_k<<<B_ * (P_ / 256), 256, 0, stream>>>(seg, hist, rloc, inv);
  gather_k<<<M_, 256, 0, stream>>>(img, inv, cnts, feats);
  gemm_k<<<(M_ / 128) * (E_ / 128), 256, 0, stream>>>(feats, Wb, bias, out);
}